// Round 7
// baseline (636.807 us; speedup 1.0000x reference)
//
#include <hip/hip_runtime.h>
#include <math.h>

#define BB 32
#define NN 16384
#define GG 128
#define KK 64
#define HH 128
#define DD 384
#define LN_EPS 1e-5f
#define NBUCK 2048
#define CANDCAP 1024

// round-to-nearest sum of 3 squares, matching jnp.sum(x**2, -1) order, no FMA contraction
__device__ __forceinline__ float sq3(float x, float y, float z) {
    return __fadd_rn(__fadd_rn(__fmul_rn(x, x), __fmul_rn(y, y)), __fmul_rn(z, z));
}

// order-preserving uint key of dist2, same formula/rounding as reference
__device__ __forceinline__ unsigned distkey(float px, float py, float pz, float4 c4) {
    float p2 = sq3(px, py, pz);
    float dot = __fadd_rn(__fadd_rn(__fmul_rn(c4.x, px), __fmul_rn(c4.y, py)),
                          __fmul_rn(c4.z, pz));
    float d = __fsub_rn(__fadd_rn(c4.w, p2), __fmul_rn(2.0f, dot));
    unsigned u = __float_as_uint(d);
    return u ^ ((u & 0x80000000u) ? 0xFFFFFFFFu : 0x80000000u);
}

// ---------------- prep: transpose w2 [128,384] -> w2t [384,128] ----------------
__global__ void prep_kernel(const float* __restrict__ w2, float* __restrict__ w2t) {
    int i = blockIdx.x * 256 + threadIdx.x;  // over DD*HH = 49152
    if (i < HH * DD) {
        int f = i >> 7;    // 0..383
        int k = i & 127;   // 0..127
        w2t[i] = w2[k * DD + f];
    }
}

// ---------------- FPS: one block per batch, 1024 threads, 16 pts/thread ------------
// Rounds 0/5/6 all converge to ~2.2us/iter with totally different streaming paths
// (global / scratch / LDS) -> streaming isn't the bound; unhidden latency at only
// 2 waves/SIMD is. This version: 1024 threads = 4 waves/SIMD (2x latency hiding),
// x,y streamed from LDS (dense ds_read_b128, 2-way bank aliasing = free), z + dist
// (32 floats ~ 70 VGPR demand) in registers -- fits the 128-VGPR/4-wave cap without
// any allocator fight (round 3's 1024-thr try needed 64 floats -> spilled at cap 64).
// Tail has NO dependent global load: winner's x,y come from the scalar-addressable
// LDS arrays (((float*)xl)[idx]); winner lane deposits z + packed key in a ping-pong
// LDS slot (round-5-proven one-barrier scheme).
__global__ __launch_bounds__(1024) void fps_kernel(const float* __restrict__ pts,
                                                   float* __restrict__ cent_out,
                                                   float4* __restrict__ cent_pad) {
    __shared__ float4 xl[NN / 4];  // 64KB: x of points 4q..4q+3 (component t = point 4q+t)
    __shared__ float4 yl[NN / 4];  // 64KB: y likewise
    __shared__ unsigned long long wkey[2][16];  // per-wave winner key, ping-pong parity
    __shared__ float wzs[2][16];                // per-wave winner z

    const int b = blockIdx.x;
    const int tid = threadIdx.x;
    const float* p = pts + (size_t)b * NN * 3;
    const float4* p4 = (const float4*)p;

    // thread owns quads q = j*1024+tid (j=0..3): points 4q..4q+3, loaded as 3 float4.
    float z[16], dist[16];
#pragma unroll
    for (int j = 0; j < 4; j++) {
        int q = j * 1024 + tid;
        float4 A = p4[3 * q], B = p4[3 * q + 1], C = p4[3 * q + 2];
        xl[q] = make_float4(A.x, A.w, B.z, C.y);
        yl[q] = make_float4(A.y, B.x, B.w, C.z);
        z[j * 4 + 0] = A.z; z[j * 4 + 1] = B.y; z[j * 4 + 2] = C.x; z[j * 4 + 3] = C.w;
#pragma unroll
        for (int t = 0; t < 4; t++) dist[j * 4 + t] = INFINITY;
    }
    __syncthreads();

    float cx = p[0], cy = p[1], cz = p[2];  // deterministic start at index 0
    const int wid = tid >> 6;

    for (int it = 0; it < GG; it++) {
        if (tid == 0) {
            float* co = cent_out + ((size_t)b * GG + it) * 3;
            co[0] = cx; co[1] = cy; co[2] = cz;
            cent_pad[b * GG + it] = make_float4(cx, cy, cz, sq3(cx, cy, cz));
        }
        if (it == GG - 1) break;  // last argmax unused
        const int par = it & 1;

        // distance update + 4-chain local argmax (strict > keeps lowest index per chain)
        float bv0 = -INFINITY, bv1 = -INFINITY, bv2 = -INFINITY, bv3 = -INFINITY;
        int bi0 = 0, bi1 = 0, bi2 = 0, bi3 = 0;
#pragma unroll
        for (int j = 0; j < 4; j++) {
            int q = j * 1024 + tid;
            int nb = 4 * q;
            float4 xs = xl[q];  // ds_read_b128, dense, immediate offset j*16384
            float4 ys = yl[q];
            {
                float dx = __fsub_rn(xs.x, cx);
                float dy = __fsub_rn(ys.x, cy);
                float dz = __fsub_rn(z[j * 4 + 0], cz);
                float d = sq3(dx, dy, dz);
                float dj = fminf(dist[j * 4 + 0], d);
                dist[j * 4 + 0] = dj;
                if (dj > bv0) { bv0 = dj; bi0 = nb + 0; }
            }
            {
                float dx = __fsub_rn(xs.y, cx);
                float dy = __fsub_rn(ys.y, cy);
                float dz = __fsub_rn(z[j * 4 + 1], cz);
                float d = sq3(dx, dy, dz);
                float dj = fminf(dist[j * 4 + 1], d);
                dist[j * 4 + 1] = dj;
                if (dj > bv1) { bv1 = dj; bi1 = nb + 1; }
            }
            {
                float dx = __fsub_rn(xs.z, cx);
                float dy = __fsub_rn(ys.z, cy);
                float dz = __fsub_rn(z[j * 4 + 2], cz);
                float d = sq3(dx, dy, dz);
                float dj = fminf(dist[j * 4 + 2], d);
                dist[j * 4 + 2] = dj;
                if (dj > bv2) { bv2 = dj; bi2 = nb + 2; }
            }
            {
                float dx = __fsub_rn(xs.w, cx);
                float dy = __fsub_rn(ys.w, cy);
                float dz = __fsub_rn(z[j * 4 + 3], cz);
                float d = sq3(dx, dy, dz);
                float dj = fminf(dist[j * 4 + 3], d);
                dist[j * 4 + 3] = dj;
                if (dj > bv3) { bv3 = dj; bi3 = nb + 3; }
            }
        }
        // merge chains, lowest index wins ties
        float mfv = bv0; int mfi = bi0;
        if (bv1 > mfv || (bv1 == mfv && bi1 < mfi)) { mfv = bv1; mfi = bi1; }
        if (bv2 > mfv || (bv2 == mfv && bi2 < mfi)) { mfv = bv2; mfi = bi2; }
        if (bv3 > mfv || (bv3 == mfv && bi3 < mfi)) { mfv = bv3; mfi = bi3; }

        // wave (64-lane) argmax reduce, lower index wins ties
        float fv = mfv; int fi = mfi;
#pragma unroll
        for (int off = 32; off >= 1; off >>= 1) {
            float ov = __shfl_down(fv, off);
            int oi = __shfl_down(fi, off);
            if (ov > fv || (ov == fv && oi < fi)) { fv = ov; fi = oi; }
        }
        int wfi = __shfl(fi, 0);  // broadcast wave winner index
        // exactly one lane owns point wfi (ownership partitions indices): it deposits
        // key + z (x,y are recoverable from LDS by anyone)
        if (mfi == wfi) {
            int jj = (wfi >> 2) - tid;  // = j*1024 for the owner
            int tt = wfi & 3;
            float sz = 0.f;
#pragma unroll
            for (int j = 0; j < 4; j++) {
                if (jj == j * 1024) {
#pragma unroll
                    for (int t = 0; t < 4; t++) {
                        if (tt == t) sz = z[j * 4 + t];
                    }
                }
            }
            // dist >= 0 so float bits are order-monotone; ~idx -> lowest index wins max
            wkey[par][wid] = ((unsigned long long)__float_as_uint(mfv) << 32) |
                             (unsigned)(0xFFFFFFFFu - (unsigned)mfi);
            wzs[par][wid] = sz;
        }
        __syncthreads();  // the only barrier per iteration
        // every thread scans the 16 wave winners (broadcast LDS reads)
        unsigned long long bk = wkey[par][0];
        int bw = 0;
#pragma unroll
        for (int w = 1; w < 16; w++) {
            unsigned long long k2 = wkey[par][w];
            if (k2 > bk) { bk = k2; bw = w; }
        }
        int idx = (int)(0xFFFFFFFFu - (unsigned)bk);
        cx = ((const float*)xl)[idx];  // broadcast scalar LDS read
        cy = ((const float*)yl)[idx];
        cz = wzs[par][bw];
        // no second barrier: next iteration writes the OTHER parity's slots; reaching
        // iteration it+2 (this parity again) requires passing it+1's barrier, which
        // requires every wave to have finished this scan.
    }
}

// ---------------- group kernel: dist2 + exact top-64 + MLP + mean + LN ----------------
// Keys are recomputed instead of cached (key[64] live across barriers spilled to
// scratch at VGPR=76). hist/cand overlay saves 8KB LDS.
__global__ __launch_bounds__(256, 6) void group_kernel(
    const float* __restrict__ pts, const float4* __restrict__ cent_pad,
    const float* __restrict__ w1, const float* __restrict__ b1,
    const float* __restrict__ w2t, const float* __restrict__ b2,
    const float* __restrict__ lns, const float* __restrict__ lnb,
    float* __restrict__ tok_out) {
    __shared__ __align__(16) union {
        unsigned hist[NBUCK];              // phase 1-2
        unsigned long long cand[CANDCAP];  // phase 3+ (hist dead after scan)
    } sh;
    __shared__ int selIdx[KK];
    __shared__ float4 localPt[KK];
    __shared__ float w1s[3 * HH];
    __shared__ float b1s[HH];
    __shared__ __align__(16) float hbar[HH];
    __shared__ float partial[256];
    __shared__ float red2[8];
    __shared__ float toks[DD];
    __shared__ int waveSum[4];
    __shared__ unsigned long long wmin[4];
    __shared__ unsigned TA_S;
    __shared__ int cntS;
    __shared__ unsigned long long lastS;
    __shared__ float muS, rstdS;

    const int tid = threadIdx.x;
    // XCD-aware swizzle: each XCD sees only 4 batches' points (768KB -> L2 resident)
    int bid = blockIdx.x;
    int xcd = bid & 7, sub = bid >> 3;
    int b = xcd * 4 + (sub >> 7);
    int g = sub & 127;

    const float* p = pts + (size_t)b * NN * 3;
    const float4* p4 = (const float4*)p;
    float4 c4 = cent_pad[b * GG + g];

    for (int i = tid; i < 3 * HH; i += 256) w1s[i] = w1[i];
    if (tid < HH) b1s[tid] = b1[tid];
    for (int i = tid; i < NBUCK; i += 256) sh.hist[i] = 0;
    if (tid == 0) cntS = 0;
    __syncthreads();

    // ---- pass 1: histogram of 11-bit key prefixes (keys recomputed later, not stored)
    for (int i = 0; i < 16; i++) {
        int t4 = i * 256 + tid;  // quad id; points 4*t4 .. 4*t4+3
        float4 A = p4[3 * t4], B = p4[3 * t4 + 1], C = p4[3 * t4 + 2];
        unsigned k0 = distkey(A.x, A.y, A.z, c4);
        unsigned k1 = distkey(A.w, B.x, B.y, c4);
        unsigned k2 = distkey(B.z, B.w, C.x, c4);
        unsigned k3 = distkey(C.y, C.z, C.w, c4);
        atomicAdd(&sh.hist[k0 >> 21], 1u);
        atomicAdd(&sh.hist[k1 >> 21], 1u);
        atomicAdd(&sh.hist[k2 >> 21], 1u);
        atomicAdd(&sh.hist[k3 >> 21], 1u);
    }
    __syncthreads();

    // ---- find boundary bucket: smallest T with cumcount(<=T) >= 64
    {
        uint4 h0 = ((const uint4*)sh.hist)[tid * 2];
        uint4 h1 = ((const uint4*)sh.hist)[tid * 2 + 1];
        int loc[8] = {(int)h0.x, (int)h0.y, (int)h0.z, (int)h0.w,
                      (int)h1.x, (int)h1.y, (int)h1.z, (int)h1.w};
        int s = 0;
#pragma unroll
        for (int j = 0; j < 8; j++) s += loc[j];
        int lane = tid & 63, wid = tid >> 6;
        int v = s;
#pragma unroll
        for (int off = 1; off < 64; off <<= 1) {
            int o = __shfl_up(v, off);
            if (lane >= off) v += o;
        }
        if (lane == 63) waveSum[wid] = v;
        __syncthreads();
        int base = 0;
        for (int w = 0; w < wid; w++) base += waveSum[w];
        int c = base + v - s;  // exclusive prefix at this thread's first bucket
#pragma unroll
        for (int j = 0; j < 8; j++) {
            if (c < KK && c + loc[j] >= KK) TA_S = (unsigned)(tid * 8 + j);
            c += loc[j];
        }
        __syncthreads();
    }
    unsigned TA = TA_S;

    // ---- pass 2: recompute keys, collect candidates in buckets <= TA (~330 expected)
    for (int i = 0; i < 16; i++) {
        int t4 = i * 256 + tid;
        float4 A = p4[3 * t4], B = p4[3 * t4 + 1], C = p4[3 * t4 + 2];
        unsigned k[4];
        k[0] = distkey(A.x, A.y, A.z, c4);
        k[1] = distkey(A.w, B.x, B.y, c4);
        k[2] = distkey(B.z, B.w, C.x, c4);
        k[3] = distkey(C.y, C.z, C.w, c4);
#pragma unroll
        for (int q = 0; q < 4; q++) {
            if ((k[q] >> 21) <= TA) {
                int pos = atomicAdd(&cntS, 1);
                if (pos < CANDCAP)
                    sh.cand[pos] =
                        ((unsigned long long)k[q] << 32) | (unsigned)(4 * t4 + q);
            }
        }
    }
    __syncthreads();
    int cnt = cntS;  // >= 64 by construction

    if (cnt <= CANDCAP) {
        // ---- exact rank-select of the 64 lexicographically smallest (key,idx)
        for (int c0 = tid; c0 < cnt; c0 += 256) {
            unsigned long long pr = sh.cand[c0];
            int rank = 0;
            for (int j = 0; j < cnt; j++) rank += (sh.cand[j] < pr);
            if (rank < KK) selIdx[rank] = (int)(unsigned)pr;
        }
        __syncthreads();
    } else {
        // ---- pathological fallback (never triggers on real data): exact 64-round
        // min-extraction, keys recomputed each round
        if (tid == 0) lastS = 0ull;
        __syncthreads();
        for (int r = 0; r < KK; r++) {
            unsigned long long last = lastS;
            unsigned long long best = 0xFFFFFFFFFFFFFFFFull;
            for (int i = 0; i < 16; i++) {
                int t4 = i * 256 + tid;
                float4 A = p4[3 * t4], B = p4[3 * t4 + 1], C = p4[3 * t4 + 2];
                unsigned k[4];
                k[0] = distkey(A.x, A.y, A.z, c4);
                k[1] = distkey(A.w, B.x, B.y, c4);
                k[2] = distkey(B.z, B.w, C.x, c4);
                k[3] = distkey(C.y, C.z, C.w, c4);
#pragma unroll
                for (int q = 0; q < 4; q++) {
                    unsigned long long pr =
                        ((unsigned long long)k[q] << 32) | (unsigned)(4 * t4 + q);
                    if ((r == 0 || pr > last) && pr < best) best = pr;
                }
            }
            unsigned blo = (unsigned)best, bhi = (unsigned)(best >> 32);
#pragma unroll
            for (int off = 32; off >= 1; off >>= 1) {
                unsigned olo = __shfl_down(blo, off);
                unsigned ohi = __shfl_down(bhi, off);
                unsigned long long ob = ((unsigned long long)ohi << 32) | olo;
                unsigned long long cur = ((unsigned long long)bhi << 32) | blo;
                if (ob < cur) { blo = olo; bhi = ohi; }
            }
            int lane = tid & 63, wid = tid >> 6;
            if (lane == 0) wmin[wid] = ((unsigned long long)bhi << 32) | blo;
            __syncthreads();
            if (tid == 0) {
                unsigned long long m = wmin[0];
                for (int w = 1; w < 4; w++) if (wmin[w] < m) m = wmin[w];
                selIdx[r] = (int)(unsigned)m;
                lastS = m;
            }
            __syncthreads();
        }
    }

    // ---- gather + local coords
    if (tid < KK) {
        int n = selIdx[tid];
        float px = p[n * 3], py = p[n * 3 + 1], pz = p[n * 3 + 2];
        localPt[tid] = make_float4(px - c4.x, py - c4.y, pz - c4.z, 0.f);
    }
    __syncthreads();
    // ---- layer1 + exact GELU + mean over K (2 threads per feature, 32 pts each)
    {
        int f = tid & 127, half = tid >> 7;
        float wa = w1s[f], wb = w1s[HH + f], wc = w1s[2 * HH + f], bb = b1s[f];
        float s = 0.f;
        for (int k = half * 32; k < half * 32 + 32; k++) {
            float4 lp = localPt[k];
            float a = lp.x * wa + lp.y * wb + lp.z * wc + bb;
            float hh = 0.5f * a * (1.0f + erff(a * 0.70710678118654752440f));
            s += hh;
        }
        partial[tid] = s;
    }
    __syncthreads();
    if (tid < HH) hbar[tid] = (partial[tid] + partial[tid + HH]) * (1.0f / 64.0f);
    __syncthreads();
    // ---- layer2: tokens = hbar @ w2 + b2   (mean commutes with the linear layer)
    for (int f2 = tid; f2 < DD; f2 += 256) {
        const float4* wrow = (const float4*)(w2t + f2 * HH);
        const float4* hb = (const float4*)hbar;
        float acc = b2[f2];
#pragma unroll 8
        for (int q = 0; q < 32; q++) {
            float4 w4 = wrow[q];
            float4 h4 = hb[q];
            acc += h4.x * w4.x + h4.y * w4.y + h4.z * w4.z + h4.w * w4.w;
        }
        toks[f2] = acc;
    }
    __syncthreads();
    // ---- LayerNorm over 384
    {
        float s1 = 0.f, s2 = 0.f;
        for (int f2 = tid; f2 < DD; f2 += 256) {
            float v = toks[f2];
            s1 += v;
            s2 += v * v;
        }
#pragma unroll
        for (int off = 32; off >= 1; off >>= 1) {
            s1 += __shfl_down(s1, off);
            s2 += __shfl_down(s2, off);
        }
        int lane = tid & 63, wid = tid >> 6;
        if (lane == 0) { partial[wid] = s1; red2[wid] = s2; }
        __syncthreads();
        if (tid == 0) {
            float t1 = partial[0] + partial[1] + partial[2] + partial[3];
            float t2 = red2[0] + red2[1] + red2[2] + red2[3];
            float mu = t1 / (float)DD;
            float var = t2 / (float)DD - mu * mu;
            muS = mu;
            rstdS = rsqrtf(var + LN_EPS);
        }
        __syncthreads();
    }
    float mu = muS, rstd = rstdS;
    float* outp = tok_out + ((size_t)b * GG + g) * DD;
    for (int f2 = tid; f2 < DD; f2 += 256) {
        outp[f2] = (toks[f2] - mu) * rstd * lns[f2] + lnb[f2];
    }
}

extern "C" void kernel_launch(void* const* d_in, const int* in_sizes, int n_in,
                              void* d_out, int out_size, void* d_ws, size_t ws_size,
                              hipStream_t stream) {
    const float* pts = (const float*)d_in[0];
    const float* w1 = (const float*)d_in[1];
    const float* b1 = (const float*)d_in[2];
    const float* w2 = (const float*)d_in[3];
    const float* b2 = (const float*)d_in[4];
    const float* lns = (const float*)d_in[5];
    const float* lnb = (const float*)d_in[6];
    float* out = (float*)d_out;

    // ws layout: cent_pad [B*G float4] = 64KB, then w2t [384*128 floats] = 192KB
    float4* cent_pad = (float4*)d_ws;
    float* w2t = (float*)((char*)d_ws + BB * GG * sizeof(float4));

    prep_kernel<<<192, 256, 0, stream>>>(w2, w2t);
    fps_kernel<<<BB, 1024, 0, stream>>>(pts, out, cent_pad);
    group_kernel<<<BB * GG, 256, 0, stream>>>(pts, cent_pad, w1, b1, w2t, b2, lns, lnb,
                                              out + BB * GG * 3);
}

// Round 8
// 533.124 us; speedup vs baseline: 1.1945x; 1.1945x over previous
//
#include <hip/hip_runtime.h>
#include <math.h>

#define BB 32
#define NN 16384
#define GG 128
#define KK 64
#define HH 128
#define DD 384
#define LN_EPS 1e-5f
#define NBUCK 2048
#define CANDCAP 1024

// round-to-nearest sum of 3 squares, matching jnp.sum(x**2, -1) order, no FMA contraction
__device__ __forceinline__ float sq3(float x, float y, float z) {
    return __fadd_rn(__fadd_rn(__fmul_rn(x, x), __fmul_rn(y, y)), __fmul_rn(z, z));
}

// order-preserving uint key of dist2, same formula/rounding as reference
__device__ __forceinline__ unsigned distkey(float px, float py, float pz, float4 c4) {
    float p2 = sq3(px, py, pz);
    float dot = __fadd_rn(__fadd_rn(__fmul_rn(c4.x, px), __fmul_rn(c4.y, py)),
                          __fmul_rn(c4.z, pz));
    float d = __fsub_rn(__fadd_rn(c4.w, p2), __fmul_rn(2.0f, dot));
    unsigned u = __float_as_uint(d);
    return u ^ ((u & 0x80000000u) ? 0xFFFFFFFFu : 0x80000000u);
}

// ---------------- prep: transpose w2 [128,384] -> w2t [384,128] ----------------
__global__ void prep_kernel(const float* __restrict__ w2, float* __restrict__ w2t) {
    int i = blockIdx.x * 256 + threadIdx.x;  // over DD*HH = 49152
    if (i < HH * DD) {
        int f = i >> 7;    // 0..383
        int k = i & 127;   // 0..127
        w2t[i] = w2[k * DD + f];
    }
}

// ---------------- FPS: one block per batch, 512 threads, 32 pts/thread ----------------
// Round-0 code, restored verbatim: measured 274us. Rounds 1-7 established this is a
// robust plateau: cross-block split (+sync cost), fusion (reg/cache destruction),
// reg pinning (allocator caps at 128), LDS streaming (same 2.2us/iter), and 1024-thr
// (per-thread-constant tail doubles) ALL lose to this structure.
__global__ __launch_bounds__(512, 2) void fps_kernel(const float* __restrict__ pts,
                                                     float* __restrict__ cent_out,
                                                     float4* __restrict__ cent_pad) {
    const int b = blockIdx.x;
    const int tid = threadIdx.x;
    const float* p = pts + (size_t)b * NN * 3;
    const float4* p4 = (const float4*)p;

    // thread owns quads q = j*512+tid (j=0..7): points 4q..4q+3, loaded as 3 float4
    float x[32], y[32], z[32], dist[32];
#pragma unroll
    for (int j = 0; j < 8; j++) {
        int q = j * 512 + tid;
        float4 A = p4[3 * q], B = p4[3 * q + 1], C = p4[3 * q + 2];
        x[j * 4 + 0] = A.x; y[j * 4 + 0] = A.y; z[j * 4 + 0] = A.z;
        x[j * 4 + 1] = A.w; y[j * 4 + 1] = B.x; z[j * 4 + 1] = B.y;
        x[j * 4 + 2] = B.z; y[j * 4 + 2] = B.w; z[j * 4 + 2] = C.x;
        x[j * 4 + 3] = C.y; y[j * 4 + 3] = C.z; z[j * 4 + 3] = C.w;
#pragma unroll
        for (int t = 0; t < 4; t++) dist[j * 4 + t] = INFINITY;
    }

    __shared__ unsigned long long slot[GG];  // one pre-zeroed slot per iteration
    for (int i = tid; i < GG; i += 512) slot[i] = 0ull;
    __syncthreads();

    float cx = p[0], cy = p[1], cz = p[2];  // deterministic start at index 0

    for (int it = 0; it < GG; it++) {
        if (tid == 0) {
            float* co = cent_out + ((size_t)b * GG + it) * 3;
            co[0] = cx; co[1] = cy; co[2] = cz;
            cent_pad[b * GG + it] = make_float4(cx, cy, cz, sq3(cx, cy, cz));
        }
        if (it == GG - 1) break;  // last argmax unused

        // distance update + 4-chain local argmax (strict > keeps lowest index per chain)
        float bv0 = -INFINITY, bv1 = -INFINITY, bv2 = -INFINITY, bv3 = -INFINITY;
        int bi0 = 0, bi1 = 0, bi2 = 0, bi3 = 0;
#pragma unroll
        for (int j = 0; j < 8; j++) {
            int nb = 4 * (j * 512 + tid);
#pragma unroll
            for (int t = 0; t < 4; t++) {
                int r = j * 4 + t;
                float dx = __fsub_rn(x[r], cx);
                float dy = __fsub_rn(y[r], cy);
                float dz = __fsub_rn(z[r], cz);
                float d = sq3(dx, dy, dz);
                float dj = fminf(dist[r], d);
                dist[r] = dj;
                int n = nb + t;
                switch (t) {
                    case 0: if (dj > bv0) { bv0 = dj; bi0 = n; } break;
                    case 1: if (dj > bv1) { bv1 = dj; bi1 = n; } break;
                    case 2: if (dj > bv2) { bv2 = dj; bi2 = n; } break;
                    case 3: if (dj > bv3) { bv3 = dj; bi3 = n; } break;
                }
            }
        }
        float fv = bv0; int fi = bi0;
        if (bv1 > fv || (bv1 == fv && bi1 < fi)) { fv = bv1; fi = bi1; }
        if (bv2 > fv || (bv2 == fv && bi2 < fi)) { fv = bv2; fi = bi2; }
        if (bv3 > fv || (bv3 == fv && bi3 < fi)) { fv = bv3; fi = bi3; }
        // wave (64-lane) argmax reduce, lower index wins ties
#pragma unroll
        for (int off = 32; off >= 1; off >>= 1) {
            float ov = __shfl_down(fv, off);
            int oi = __shfl_down(fi, off);
            if (ov > fv || (ov == fv && oi < fi)) { fv = ov; fi = oi; }
        }
        // dist >= 0 so float bits are order-monotone; ~idx -> lowest index wins max
        if ((tid & 63) == 0) {
            unsigned long long packed =
                ((unsigned long long)__float_as_uint(fv) << 32) |
                (unsigned)(0xFFFFFFFFu - (unsigned)fi);
            atomicMax(&slot[it], packed);
        }
        __syncthreads();  // the only barrier per iteration
        unsigned long long w = slot[it];
        int idx = (int)(0xFFFFFFFFu - (unsigned)w);
        const float* wp = p + (size_t)idx * 3;  // broadcast same-address load, L2-hit
        cx = wp[0]; cy = wp[1]; cz = wp[2];
    }
}

// ---------------- group kernel: dist2 + exact top-64 + MLP + mean + LN ----------------
// Round-0 structure. ONE change this round: the rank-select scan batches 8 independent
// LDS reads per iteration. The old per-iteration read->compare dependency exposed
// ~330 x ~40cy of serial LDS latency per wave (instruction accounting shows group is
// ~70% stalled, not issue-bound); 8 reads in flight under one lgkmcnt amortize it.
// Rank is an order-independent exact sum of u64 compares -> zero numerics risk.
__global__ __launch_bounds__(256, 6) void group_kernel(
    const float* __restrict__ pts, const float4* __restrict__ cent_pad,
    const float* __restrict__ w1, const float* __restrict__ b1,
    const float* __restrict__ w2t, const float* __restrict__ b2,
    const float* __restrict__ lns, const float* __restrict__ lnb,
    float* __restrict__ tok_out) {
    __shared__ __align__(16) union {
        unsigned hist[NBUCK];              // phase 1-2
        unsigned long long cand[CANDCAP];  // phase 3+ (hist dead after scan)
    } sh;
    __shared__ int selIdx[KK];
    __shared__ float4 localPt[KK];
    __shared__ float w1s[3 * HH];
    __shared__ float b1s[HH];
    __shared__ __align__(16) float hbar[HH];
    __shared__ float partial[256];
    __shared__ float red2[8];
    __shared__ float toks[DD];
    __shared__ int waveSum[4];
    __shared__ unsigned long long wmin[4];
    __shared__ unsigned TA_S;
    __shared__ int cntS;
    __shared__ unsigned long long lastS;
    __shared__ float muS, rstdS;

    const int tid = threadIdx.x;
    // XCD-aware swizzle: each XCD sees only 4 batches' points (768KB -> L2 resident)
    int bid = blockIdx.x;
    int xcd = bid & 7, sub = bid >> 3;
    int b = xcd * 4 + (sub >> 7);
    int g = sub & 127;

    const float* p = pts + (size_t)b * NN * 3;
    const float4* p4 = (const float4*)p;
    float4 c4 = cent_pad[b * GG + g];

    for (int i = tid; i < 3 * HH; i += 256) w1s[i] = w1[i];
    if (tid < HH) b1s[tid] = b1[tid];
    for (int i = tid; i < NBUCK; i += 256) sh.hist[i] = 0;
    if (tid == 0) cntS = 0;
    __syncthreads();

    // ---- pass 1: histogram of 11-bit key prefixes (keys recomputed later, not stored)
    for (int i = 0; i < 16; i++) {
        int t4 = i * 256 + tid;  // quad id; points 4*t4 .. 4*t4+3
        float4 A = p4[3 * t4], B = p4[3 * t4 + 1], C = p4[3 * t4 + 2];
        unsigned k0 = distkey(A.x, A.y, A.z, c4);
        unsigned k1 = distkey(A.w, B.x, B.y, c4);
        unsigned k2 = distkey(B.z, B.w, C.x, c4);
        unsigned k3 = distkey(C.y, C.z, C.w, c4);
        atomicAdd(&sh.hist[k0 >> 21], 1u);
        atomicAdd(&sh.hist[k1 >> 21], 1u);
        atomicAdd(&sh.hist[k2 >> 21], 1u);
        atomicAdd(&sh.hist[k3 >> 21], 1u);
    }
    __syncthreads();

    // ---- find boundary bucket: smallest T with cumcount(<=T) >= 64
    {
        uint4 h0 = ((const uint4*)sh.hist)[tid * 2];
        uint4 h1 = ((const uint4*)sh.hist)[tid * 2 + 1];
        int loc[8] = {(int)h0.x, (int)h0.y, (int)h0.z, (int)h0.w,
                      (int)h1.x, (int)h1.y, (int)h1.z, (int)h1.w};
        int s = 0;
#pragma unroll
        for (int j = 0; j < 8; j++) s += loc[j];
        int lane = tid & 63, wid = tid >> 6;
        int v = s;
#pragma unroll
        for (int off = 1; off < 64; off <<= 1) {
            int o = __shfl_up(v, off);
            if (lane >= off) v += o;
        }
        if (lane == 63) waveSum[wid] = v;
        __syncthreads();
        int base = 0;
        for (int w = 0; w < wid; w++) base += waveSum[w];
        int c = base + v - s;  // exclusive prefix at this thread's first bucket
#pragma unroll
        for (int j = 0; j < 8; j++) {
            if (c < KK && c + loc[j] >= KK) TA_S = (unsigned)(tid * 8 + j);
            c += loc[j];
        }
        __syncthreads();
    }
    unsigned TA = TA_S;

    // ---- pass 2: recompute keys, collect candidates in buckets <= TA (~330 expected)
    for (int i = 0; i < 16; i++) {
        int t4 = i * 256 + tid;
        float4 A = p4[3 * t4], B = p4[3 * t4 + 1], C = p4[3 * t4 + 2];
        unsigned k[4];
        k[0] = distkey(A.x, A.y, A.z, c4);
        k[1] = distkey(A.w, B.x, B.y, c4);
        k[2] = distkey(B.z, B.w, C.x, c4);
        k[3] = distkey(C.y, C.z, C.w, c4);
#pragma unroll
        for (int q = 0; q < 4; q++) {
            if ((k[q] >> 21) <= TA) {
                int pos = atomicAdd(&cntS, 1);
                if (pos < CANDCAP)
                    sh.cand[pos] =
                        ((unsigned long long)k[q] << 32) | (unsigned)(4 * t4 + q);
            }
        }
    }
    __syncthreads();
    int cnt = cntS;  // >= 64 by construction

    if (cnt <= CANDCAP) {
        // ---- exact rank-select of the 64 lexicographically smallest (key,idx)
        // 8-way batched scan: 8 independent ds_reads in flight per iteration instead of
        // a serial read->compare chain (the round-8 change).
        for (int c0 = tid; c0 < cnt; c0 += 256) {
            unsigned long long pr = sh.cand[c0];
            int rank = 0;
            int j = 0;
            for (; j + 8 <= cnt; j += 8) {
                unsigned long long a0 = sh.cand[j + 0];
                unsigned long long a1 = sh.cand[j + 1];
                unsigned long long a2 = sh.cand[j + 2];
                unsigned long long a3 = sh.cand[j + 3];
                unsigned long long a4 = sh.cand[j + 4];
                unsigned long long a5 = sh.cand[j + 5];
                unsigned long long a6 = sh.cand[j + 6];
                unsigned long long a7 = sh.cand[j + 7];
                rank += (int)(a0 < pr) + (int)(a1 < pr) + (int)(a2 < pr) +
                        (int)(a3 < pr) + (int)(a4 < pr) + (int)(a5 < pr) +
                        (int)(a6 < pr) + (int)(a7 < pr);
            }
            for (; j < cnt; j++) rank += (int)(sh.cand[j] < pr);
            if (rank < KK) selIdx[rank] = (int)(unsigned)pr;
        }
        __syncthreads();
    } else {
        // ---- pathological fallback (never triggers on real data): exact 64-round
        // min-extraction, keys recomputed each round
        if (tid == 0) lastS = 0ull;
        __syncthreads();
        for (int r = 0; r < KK; r++) {
            unsigned long long last = lastS;
            unsigned long long best = 0xFFFFFFFFFFFFFFFFull;
            for (int i = 0; i < 16; i++) {
                int t4 = i * 256 + tid;
                float4 A = p4[3 * t4], B = p4[3 * t4 + 1], C = p4[3 * t4 + 2];
                unsigned k[4];
                k[0] = distkey(A.x, A.y, A.z, c4);
                k[1] = distkey(A.w, B.x, B.y, c4);
                k[2] = distkey(B.z, B.w, C.x, c4);
                k[3] = distkey(C.y, C.z, C.w, c4);
#pragma unroll
                for (int q = 0; q < 4; q++) {
                    unsigned long long pr =
                        ((unsigned long long)k[q] << 32) | (unsigned)(4 * t4 + q);
                    if ((r == 0 || pr > last) && pr < best) best = pr;
                }
            }
            unsigned blo = (unsigned)best, bhi = (unsigned)(best >> 32);
#pragma unroll
            for (int off = 32; off >= 1; off >>= 1) {
                unsigned olo = __shfl_down(blo, off);
                unsigned ohi = __shfl_down(bhi, off);
                unsigned long long ob = ((unsigned long long)ohi << 32) | olo;
                unsigned long long cur = ((unsigned long long)bhi << 32) | blo;
                if (ob < cur) { blo = olo; bhi = ohi; }
            }
            int lane = tid & 63, wid = tid >> 6;
            if (lane == 0) wmin[wid] = ((unsigned long long)bhi << 32) | blo;
            __syncthreads();
            if (tid == 0) {
                unsigned long long m = wmin[0];
                for (int w = 1; w < 4; w++) if (wmin[w] < m) m = wmin[w];
                selIdx[r] = (int)(unsigned)m;
                lastS = m;
            }
            __syncthreads();
        }
    }

    // ---- gather + local coords
    if (tid < KK) {
        int n = selIdx[tid];
        float px = p[n * 3], py = p[n * 3 + 1], pz = p[n * 3 + 2];
        localPt[tid] = make_float4(px - c4.x, py - c4.y, pz - c4.z, 0.f);
    }
    __syncthreads();
    // ---- layer1 + exact GELU + mean over K (2 threads per feature, 32 pts each)
    {
        int f = tid & 127, half = tid >> 7;
        float wa = w1s[f], wb = w1s[HH + f], wc = w1s[2 * HH + f], bb = b1s[f];
        float s = 0.f;
        for (int k = half * 32; k < half * 32 + 32; k++) {
            float4 lp = localPt[k];
            float a = lp.x * wa + lp.y * wb + lp.z * wc + bb;
            float hh = 0.5f * a * (1.0f + erff(a * 0.70710678118654752440f));
            s += hh;
        }
        partial[tid] = s;
    }
    __syncthreads();
    if (tid < HH) hbar[tid] = (partial[tid] + partial[tid + HH]) * (1.0f / 64.0f);
    __syncthreads();
    // ---- layer2: tokens = hbar @ w2 + b2   (mean commutes with the linear layer)
    for (int f2 = tid; f2 < DD; f2 += 256) {
        const float4* wrow = (const float4*)(w2t + f2 * HH);
        const float4* hb = (const float4*)hbar;
        float acc = b2[f2];
#pragma unroll 8
        for (int q = 0; q < 32; q++) {
            float4 w4 = wrow[q];
            float4 h4 = hb[q];
            acc += h4.x * w4.x + h4.y * w4.y + h4.z * w4.z + h4.w * w4.w;
        }
        toks[f2] = acc;
    }
    __syncthreads();
    // ---- LayerNorm over 384
    {
        float s1 = 0.f, s2 = 0.f;
        for (int f2 = tid; f2 < DD; f2 += 256) {
            float v = toks[f2];
            s1 += v;
            s2 += v * v;
        }
#pragma unroll
        for (int off = 32; off >= 1; off >>= 1) {
            s1 += __shfl_down(s1, off);
            s2 += __shfl_down(s2, off);
        }
        int lane = tid & 63, wid = tid >> 6;
        if (lane == 0) { partial[wid] = s1; red2[wid] = s2; }
        __syncthreads();
        if (tid == 0) {
            float t1 = partial[0] + partial[1] + partial[2] + partial[3];
            float t2 = red2[0] + red2[1] + red2[2] + red2[3];
            float mu = t1 / (float)DD;
            float var = t2 / (float)DD - mu * mu;
            muS = mu;
            rstdS = rsqrtf(var + LN_EPS);
        }
        __syncthreads();
    }
    float mu = muS, rstd = rstdS;
    float* outp = tok_out + ((size_t)b * GG + g) * DD;
    for (int f2 = tid; f2 < DD; f2 += 256) {
        outp[f2] = (toks[f2] - mu) * rstd * lns[f2] + lnb[f2];
    }
}

extern "C" void kernel_launch(void* const* d_in, const int* in_sizes, int n_in,
                              void* d_out, int out_size, void* d_ws, size_t ws_size,
                              hipStream_t stream) {
    const float* pts = (const float*)d_in[0];
    const float* w1 = (const float*)d_in[1];
    const float* b1 = (const float*)d_in[2];
    const float* w2 = (const float*)d_in[3];
    const float* b2 = (const float*)d_in[4];
    const float* lns = (const float*)d_in[5];
    const float* lnb = (const float*)d_in[6];
    float* out = (float*)d_out;

    // ws layout: cent_pad [B*G float4] = 64KB, then w2t [384*128 floats] = 192KB
    float4* cent_pad = (float4*)d_ws;
    float* w2t = (float*)((char*)d_ws + BB * GG * sizeof(float4));

    prep_kernel<<<192, 256, 0, stream>>>(w2, w2t);
    fps_kernel<<<BB, 512, 0, stream>>>(pts, out, cent_pad);
    group_kernel<<<BB * GG, 256, 0, stream>>>(pts, cent_pad, w1, b1, w2t, b2, lns, lnb,
                                              out + BB * GG * 3);
}